// Round 1
// baseline (929.478 us; speedup 1.0000x reference)
//
#include <hip/hip_runtime.h>
#include <math.h>

// ReAttention fp32 baseline (round 1: correctness + profile anchor).
// B=8 N=1024 D=512 H=8 dh=64 inner=512.
//
// Math notes:
//  - softmax rows sum to 1  => BN mean of conv output = sum_h c_gh/N + b_g;
//    conv bias b_g cancels in train-mode BN entirely.
//  - attn'' = alpha_g * u_g + c_g  with u_g = sum_h conv_w[g,h] * S_h,
//    alpha_g = gamma*rsqrt(var+eps), c_g = beta - E[u]*alpha.
//  - out_inner[b,n,g*64+d] = alpha_g*O1[b,g,n,d] + c_g*vsum[b,g,d],
//    O1 = sum_m u_g[n,m] v_g[m,d]  (alpha-independent => stats can be
//    accumulated in the same pass that builds O1).

#define Bz 8
#define Nn 1024
#define Dd 512
#define Hh 8
#define DH 64
#define INNER 512
#define QW 1536
#define SCALE 0.125f
#define BN_EPS 1e-5f

// ws layout (floats)
#define WS_QKV 0
#define WS_RSUM (WS_QKV + (size_t)Bz * Nn * QW)            // 12,582,912
#define WS_O1 (WS_RSUM + (size_t)Bz * Hh * Nn)             // + 65,536
#define WS_VSUM (WS_O1 + (size_t)Bz * Hh * Nn * DH)        // + 4,194,304
#define WS_STATS (WS_VSUM + (size_t)Bz * Hh * DH)          // + 4,096
#define WS_AC (WS_STATS + 16)

// ---------------- K0: qkv = x @ w_qkv  [8192x512]@[512x1536] ----------------
__global__ __launch_bounds__(256) void k_gemm_qkv(const float* __restrict__ X,
                                                  const float* __restrict__ W,
                                                  float* __restrict__ C) {
  __shared__ float sA[16][68];  // [k][m], pad 4
  __shared__ float sB[16][68];  // [k][n]
  const int t = threadIdx.x;
  const int row0 = blockIdx.y * 64;
  const int col0 = blockIdx.x * 64;
  const int tm = (t >> 4) << 2;
  const int tn = (t & 15) << 2;
  const int la_m = t >> 2, la_k = (t & 3) << 2;
  const int lb_k = t >> 4, lb_n = (t & 15) << 2;
  float acc[4][4] = {};
  const float* Xp = X + (size_t)(row0 + la_m) * Dd + la_k;
  const float* Wp = W + (size_t)lb_k * QW + col0 + lb_n;
  for (int k0 = 0; k0 < Dd; k0 += 16) {
    float4 a = *(const float4*)(Xp + k0);
    float4 b = *(const float4*)(Wp + (size_t)k0 * QW);
    sA[la_k + 0][la_m] = a.x;
    sA[la_k + 1][la_m] = a.y;
    sA[la_k + 2][la_m] = a.z;
    sA[la_k + 3][la_m] = a.w;
    *(float4*)&sB[lb_k][lb_n] = b;
    __syncthreads();
#pragma unroll
    for (int kk = 0; kk < 16; kk++) {
      float av[4], bv[4];
      *(float4*)av = *(const float4*)&sA[kk][tm];
      *(float4*)bv = *(const float4*)&sB[kk][tn];
#pragma unroll
      for (int i = 0; i < 4; i++)
#pragma unroll
        for (int j = 0; j < 4; j++) acc[i][j] += av[i] * bv[j];
    }
    __syncthreads();
  }
#pragma unroll
  for (int i = 0; i < 4; i++) {
    *(float4*)(C + (size_t)(row0 + tm + i) * QW + col0 + tn) =
        make_float4(acc[i][0], acc[i][1], acc[i][2], acc[i][3]);
  }
}

// ---------------- K1: softmax row sums (no max-sub; logits ~N(0,1)) --------
__global__ __launch_bounds__(256) void k_rowsum(const float* __restrict__ qkv,
                                                float* __restrict__ rsum) {
  const int b = blockIdx.z, h = blockIdx.y, n0 = blockIdx.x * 64;
  __shared__ float sQ[64][68];
  __shared__ float sK[64][68];
  __shared__ float red[64][17];
  const int t = threadIdx.x;
  const int tn = t & 15;   // rows: tn + 16*i
  const int tmg = t >> 4;  // cols: tmg + 16*j
  float rs[4] = {0.f, 0.f, 0.f, 0.f};
  for (int i = t; i < 64 * 16; i += 256) {
    int r = i >> 4, c = (i & 15) << 2;
    *(float4*)&sQ[r][c] =
        *(const float4*)(qkv + (size_t)(b * Nn + n0 + r) * QW + h * DH + c);
  }
  for (int m0 = 0; m0 < Nn; m0 += 64) {
    __syncthreads();
    for (int i = t; i < 64 * 16; i += 256) {
      int r = i >> 4, c = (i & 15) << 2;
      *(float4*)&sK[r][c] = *(const float4*)(qkv + (size_t)(b * Nn + m0 + r) * QW +
                                             INNER + h * DH + c);
    }
    __syncthreads();
    float acc[4][4] = {};
    for (int d = 0; d < 64; d += 4) {
      float qv[4][4], kv[4][4];
#pragma unroll
      for (int i = 0; i < 4; i++) *(float4*)qv[i] = *(const float4*)&sQ[tn + 16 * i][d];
#pragma unroll
      for (int j = 0; j < 4; j++) *(float4*)kv[j] = *(const float4*)&sK[tmg + 16 * j][d];
#pragma unroll
      for (int i = 0; i < 4; i++)
#pragma unroll
        for (int j = 0; j < 4; j++)
#pragma unroll
          for (int dd = 0; dd < 4; dd++) acc[i][j] += qv[i][dd] * kv[j][dd];
    }
#pragma unroll
    for (int i = 0; i < 4; i++)
#pragma unroll
      for (int j = 0; j < 4; j++) rs[i] += __expf(acc[i][j] * SCALE);
  }
  __syncthreads();
#pragma unroll
  for (int i = 0; i < 4; i++) red[tn + 16 * i][tmg] = rs[i];
  __syncthreads();
  if (t < 64) {
    float s = 0.f;
#pragma unroll
    for (int j = 0; j < 16; j++) s += red[t][j];
    rsum[(size_t)(b * Hh + h) * Nn + n0 + t] = s;
  }
}

// ---------------- Kvsum: vsum[b,g,d] = sum_m v[b,g,m,d] --------------------
__global__ __launch_bounds__(64) void k_vsum(const float* __restrict__ qkv,
                                             float* __restrict__ vsum) {
  const int g = blockIdx.x, b = blockIdx.y, d = threadIdx.x;
  const float* p = qkv + (size_t)b * Nn * QW + 2 * INNER + g * DH + d;
  float s = 0.f;
  for (int m = 0; m < Nn; m++) s += p[(size_t)m * QW];
  vsum[(size_t)(b * Hh + g) * DH + d] = s;
}

// ---------------- K2: fused S-recompute, conv mix, stats, S@V --------------
// grid (64 n-tiles, 8 b); block 512 = 8 waves; wave w handles head/g = w.
__global__ __launch_bounds__(512) void k_attn(const float* __restrict__ qkv,
                                              const float* __restrict__ rsum,
                                              const float* __restrict__ conv_w,
                                              float* __restrict__ O1,
                                              float* __restrict__ stats) {
  __shared__ float sQ[16][516];       // 33,024 B  (stride 516 ≡ 4 mod 32)
  __shared__ float sKV[18432];        // 73,728 B  k:[h][m][d] s68 / v:[g][m][d] s68
  __shared__ float sS[8 * 577];       // 18,464 B  plane 577, row 36
  __shared__ float sRs[8][16];
  __shared__ float sCw[64];
  __shared__ float sRed[8][16];
  const int b = blockIdx.y;
  const int n0 = blockIdx.x * 16;
  const int t = threadIdx.x;
  const int h = t >> 6;  // wave id == head (logits) == g (O1)
  const int sub = t & 63;
  const int rn = sub >> 3;  // logits rows: n = 2*rn + j
  const int rm = sub & 7;   // logits cols: m = rm + 8*jm (conflict-free spread)
  const int orn = sub >> 2;         // O1 row 0..15
  const int ord = (sub & 3) << 4;   // O1 d0
  const int mixn = t >> 5, mixm = t & 31;

  for (int i = t; i < 16 * 128; i += 512) {
    int r = i >> 7, c = (i & 127) << 2;
    *(float4*)&sQ[r][c] = *(const float4*)(qkv + (size_t)(b * Nn + n0 + r) * QW + c);
  }
  if (t < 64) sCw[t] = conv_w[t];
  if (t < 128)
    sRs[t >> 4][t & 15] = rsum[(size_t)(b * Hh + (t >> 4)) * Nn + n0 + (t & 15)];
  __syncthreads();
  const float rinv0 = 1.f / sRs[h][2 * rn];
  const float rinv1 = 1.f / sRs[h][2 * rn + 1];

  float o1acc[16] = {};
  float su[8] = {}, su2[8] = {};

  for (int m0 = 0; m0 < Nn; m0 += 32) {
    __syncthreads();  // prev iter's sKV(v) reads done
    // stage K tile, all 8 heads: [h][m][d] stride 68
    for (int i = t; i < 8 * 32 * 16; i += 512) {
      int hh = i >> 9, mm = (i >> 4) & 31, cc = (i & 15) << 2;
      *(float4*)&sKV[(hh * 32 + mm) * 68 + cc] = *(const float4*)(
          qkv + (size_t)(b * Nn + m0 + mm) * QW + INNER + hh * DH + cc);
    }
    __syncthreads();
    // logits for head h: 2n x 4m per thread
    float acc[2][4] = {};
    for (int d = 0; d < 64; d += 4) {
      float q0[4], q1[4], kv[4][4];
      *(float4*)q0 = *(const float4*)&sQ[2 * rn][h * DH + d];
      *(float4*)q1 = *(const float4*)&sQ[2 * rn + 1][h * DH + d];
#pragma unroll
      for (int jm = 0; jm < 4; jm++)
        *(float4*)kv[jm] = *(const float4*)&sKV[(h * 32 + rm + 8 * jm) * 68 + d];
#pragma unroll
      for (int jm = 0; jm < 4; jm++)
#pragma unroll
        for (int dd = 0; dd < 4; dd++) {
          acc[0][jm] += q0[dd] * kv[jm][dd];
          acc[1][jm] += q1[dd] * kv[jm][dd];
        }
    }
#pragma unroll
    for (int jm = 0; jm < 4; jm++) {
      sS[h * 577 + (2 * rn) * 36 + rm + 8 * jm] = __expf(acc[0][jm] * SCALE) * rinv0;
      sS[h * 577 + (2 * rn + 1) * 36 + rm + 8 * jm] = __expf(acc[1][jm] * SCALE) * rinv1;
    }
    __syncthreads();  // S complete, k reads complete
    // stage V tile (overwrite sKV): [g][m][d] stride 68
    for (int i = t; i < 8 * 32 * 16; i += 512) {
      int gg = i >> 9, mm = (i >> 4) & 31, cc = (i & 15) << 2;
      *(float4*)&sKV[(gg * 32 + mm) * 68 + cc] = *(const float4*)(
          qkv + (size_t)(b * Nn + m0 + mm) * QW + 2 * INNER + gg * DH + cc);
    }
    // conv mix in place (each thread owns one (n,m) across all planes) + stats
    {
      float sv[8], uv[8];
      const int pos = mixn * 36 + mixm;
#pragma unroll
      for (int hh = 0; hh < 8; hh++) sv[hh] = sS[hh * 577 + pos];
#pragma unroll
      for (int g = 0; g < 8; g++) {
        float u = 0.f;
#pragma unroll
        for (int hh = 0; hh < 8; hh++) u += sCw[g * 8 + hh] * sv[hh];
        uv[g] = u;
        su[g] += u;
        su2[g] += u * u;
      }
#pragma unroll
      for (int g = 0; g < 8; g++) sS[g * 577 + pos] = uv[g];
    }
    __syncthreads();  // u + v ready
    // O1 accumulate: wave's g, rows orn, d chunk ord..ord+15
    for (int m = 0; m < 32; m++) {
      float u = sS[h * 577 + orn * 36 + m];
      const float* vb = &sKV[(h * 32 + m) * 68 + ord];
#pragma unroll
      for (int q4 = 0; q4 < 4; q4++) {
        float vv[4];
        *(float4*)vv = *(const float4*)(vb + q4 * 4);
#pragma unroll
        for (int dd = 0; dd < 4; dd++) o1acc[q4 * 4 + dd] += u * vv[dd];
      }
    }
  }
  // write O1
  {
    size_t obase = (((size_t)b * Hh + h) * Nn + n0 + orn) * DH + ord;
#pragma unroll
    for (int q4 = 0; q4 < 4; q4++)
      *(float4*)(O1 + obase + q4 * 4) = make_float4(o1acc[q4 * 4], o1acc[q4 * 4 + 1],
                                                    o1acc[q4 * 4 + 2], o1acc[q4 * 4 + 3]);
  }
  // stats: wave reduce then block reduce then atomicAdd
#pragma unroll
  for (int g = 0; g < 8; g++)
    for (int off = 32; off; off >>= 1) {
      su[g] += __shfl_down(su[g], off);
      su2[g] += __shfl_down(su2[g], off);
    }
  if (sub == 0) {
#pragma unroll
    for (int g = 0; g < 8; g++) {
      sRed[h][g] = su[g];
      sRed[h][8 + g] = su2[g];
    }
  }
  __syncthreads();
  if (t < 16) {
    float s = 0.f;
#pragma unroll
    for (int w = 0; w < 8; w++) s += sRed[w][t];
    atomicAdd(&stats[t], s);
  }
}

// ---------------- K3: alpha/const from stats -------------------------------
__global__ void k_alpha(const float* __restrict__ stats,
                        const float* __restrict__ bn_gamma,
                        const float* __restrict__ bn_beta, float* __restrict__ ac) {
  int g = threadIdx.x;
  if (g < 8) {
    const float cnt = (float)Bz * (float)Nn * (float)Nn;
    float Eu = stats[g] / cnt;
    float Eu2 = stats[8 + g] / cnt;
    float var = Eu2 - Eu * Eu;
    float inv = rsqrtf(var + BN_EPS);
    float alpha = bn_gamma[g] * inv;
    ac[g] = alpha;
    ac[8 + g] = bn_beta[g] - Eu * alpha;
  }
}

// ---------------- K4: out = (alpha*O1 + c*vsum) @ w_out + b_out ------------
__global__ __launch_bounds__(256) void k_out(const float* __restrict__ O1,
                                             const float* __restrict__ vsum,
                                             const float* __restrict__ ac,
                                             const float* __restrict__ Wout,
                                             const float* __restrict__ bout,
                                             float* __restrict__ out) {
  __shared__ float sA[16][68];
  __shared__ float sB[16][68];
  __shared__ float sAl[16];
  const int t = threadIdx.x;
  if (t < 16) sAl[t] = ac[t];
  const int row0 = blockIdx.y * 64;
  const int col0 = blockIdx.x * 64;
  const int tm = (t >> 4) << 2;
  const int tn = (t & 15) << 2;
  const int la_m = t >> 2, la_k = (t & 3) << 2;
  const int lb_k = t >> 4, lb_n = (t & 15) << 2;
  const int r = row0 + la_m;
  const int bb = r >> 10, nn = r & 1023;
  float acc[4][4] = {};
  __syncthreads();  // sAl ready before A-load transform
  for (int k0 = 0; k0 < INNER; k0 += 16) {
    const int c = k0 + la_k;
    const int g = c >> 6, dd = c & 63;
    const float al = sAl[g], cc = sAl[8 + g];
    float4 o4 = *(const float4*)(O1 + (((size_t)bb * Hh + g) * Nn + nn) * DH + dd);
    float4 v4 = *(const float4*)(vsum + ((size_t)bb * Hh + g) * DH + dd);
    sA[la_k + 0][la_m] = al * o4.x + cc * v4.x;
    sA[la_k + 1][la_m] = al * o4.y + cc * v4.y;
    sA[la_k + 2][la_m] = al * o4.z + cc * v4.z;
    sA[la_k + 3][la_m] = al * o4.w + cc * v4.w;
    *(float4*)&sB[lb_k][lb_n] =
        *(const float4*)(Wout + (size_t)(k0 + lb_k) * Dd + col0 + lb_n);
    __syncthreads();
#pragma unroll
    for (int kk = 0; kk < 16; kk++) {
      float av[4], bv[4];
      *(float4*)av = *(const float4*)&sA[kk][tm];
      *(float4*)bv = *(const float4*)&sB[kk][tn];
#pragma unroll
      for (int i = 0; i < 4; i++)
#pragma unroll
        for (int j = 0; j < 4; j++) acc[i][j] += av[i] * bv[j];
    }
    __syncthreads();
  }
#pragma unroll
  for (int i = 0; i < 4; i++) {
    float4 o = make_float4(acc[i][0] + bout[col0 + tn + 0], acc[i][1] + bout[col0 + tn + 1],
                           acc[i][2] + bout[col0 + tn + 2], acc[i][3] + bout[col0 + tn + 3]);
    *(float4*)(out + (size_t)(row0 + tm + i) * Dd + col0 + tn) = o;
  }
}

extern "C" void kernel_launch(void* const* d_in, const int* in_sizes, int n_in,
                              void* d_out, int out_size, void* d_ws, size_t ws_size,
                              hipStream_t stream) {
  const float* x = (const float*)d_in[0];
  const float* w_qkv = (const float*)d_in[1];
  const float* conv_w = (const float*)d_in[2];
  // d_in[3] = conv_b : cancels in train-mode BN, unused.
  const float* bn_gamma = (const float*)d_in[4];
  const float* bn_beta = (const float*)d_in[5];
  const float* w_out = (const float*)d_in[6];
  const float* b_out = (const float*)d_in[7];
  float* ws = (float*)d_ws;
  float* qkv = ws + WS_QKV;
  float* rsum = ws + WS_RSUM;
  float* O1 = ws + WS_O1;
  float* vsum = ws + WS_VSUM;
  float* stats = ws + WS_STATS;
  float* ac = ws + WS_AC;

  hipMemsetAsync(stats, 0, 16 * sizeof(float), stream);
  k_gemm_qkv<<<dim3(QW / 64, (Bz * Nn) / 64), 256, 0, stream>>>(x, w_qkv, qkv);
  k_rowsum<<<dim3(Nn / 64, Hh, Bz), 256, 0, stream>>>(qkv, rsum);
  k_vsum<<<dim3(Hh, Bz), 64, 0, stream>>>(qkv, vsum);
  k_attn<<<dim3(Nn / 16, Bz), 512, 0, stream>>>(qkv, rsum, conv_w, O1, stats);
  k_alpha<<<1, 64, 0, stream>>>(stats, bn_gamma, bn_beta, ac);
  k_out<<<dim3(Dd / 64, (Bz * Nn) / 64), 256, 0, stream>>>(O1, vsum, ac, w_out, b_out,
                                                           (float*)d_out);
}

// Round 2
// 317.613 us; speedup vs baseline: 2.9264x; 2.9264x over previous
//
#include <hip/hip_runtime.h>
#include <math.h>

// ReAttention bf16-MFMA pipeline (round 2).
// B=8 N=1024 D=512 H=8 dh=64 inner=512.
//
//  - conv bias cancels in train-mode BN (shifts mean only).
//  - attn'' = alpha_g*u_g + c_g ; u_g = sum_h conv_w[g,h]*S_h
//  - out_inner = alpha_g*O1 + c_g*vsum ; O1 = u @ v  (alpha-independent)
//  - K0 writes v TRANSPOSED (vT[b,g,d,m]) so S@V's B-operand (k=m contiguous)
//    stages with b128 — no per-iter LDS transpose.
//  - k_attn pass0 computes softmax denominators with the SAME MFMA logits as
//    pass1 (bitwise-consistent).

#define Bz 8
#define Nn 1024
#define Dd 512
#define Hh 8
#define DH 64
#define INNER 512
#define QW 1536
#define SCALE 0.125f
#define BN_EPS 1e-5f

typedef short bf16x8 __attribute__((ext_vector_type(8)));
typedef float f32x4 __attribute__((ext_vector_type(4)));

#define MFMA(a, b, c) __builtin_amdgcn_mfma_f32_16x16x32_bf16((a), (b), (c), 0, 0, 0)

__device__ __forceinline__ unsigned short f2b(float f) {
  union { float f; unsigned u; } v; v.f = f;
  unsigned r = v.u + 0x7fffu + ((v.u >> 16) & 1u);
  return (unsigned short)(r >> 16);
}
__device__ __forceinline__ float b2f(unsigned short s) {
  union { unsigned u; float f; } v; v.u = ((unsigned)s) << 16;
  return v.f;
}

// ws layout (bytes)
#define WB_QKV 0u                          // 8192*1536*2 = 25,165,824 (q,k only)
#define WB_VT (WB_QKV + 25165824u)         // 8*8*64*1024*2 = 8,388,608
#define WB_WQT (WB_VT + 8388608u)          // 1536*512*2 = 1,572,864
#define WB_WOT (WB_WQT + 1572864u)         // 512*512*2 = 524,288
#define WB_O1 (WB_WOT + 524288u)           // 8*8*1024*64*4 = 16,777,216
#define WB_VSUM (WB_O1 + 16777216u)        // 4096*4 = 16,384
#define WB_STATS (WB_VSUM + 16384u)        // 64
#define WB_AC (WB_STATS + 64u)             // 64

// ---------------- transpose fp32 -> bf16: dst[C][R] = src[R][C]^T ----------
__global__ __launch_bounds__(256) void k_transpose(const float* __restrict__ src,
                                                   unsigned short* __restrict__ dst,
                                                   int R, int C) {
  __shared__ float tile[32][33];
  const int tc = blockIdx.x * 32, tr = blockIdx.y * 32;
  const int lx = threadIdx.x & 31, ly = threadIdx.x >> 5;
#pragma unroll
  for (int i = 0; i < 32; i += 8)
    tile[ly + i][lx] = src[(size_t)(tr + ly + i) * C + tc + lx];
  __syncthreads();
#pragma unroll
  for (int i = 0; i < 32; i += 8)
    dst[(size_t)(tc + ly + i) * R + tr + lx] = f2b(tile[lx][ly + i]);
}

// ---------------- K0: qkv = x @ w_qkv (bf16 MFMA) --------------------------
// writes q,k into qkv[row][col] bf16; v-cols into vT[b][g][d][m] bf16.
__global__ __launch_bounds__(256) void k_qkv(const float* __restrict__ X,
                                             const unsigned short* __restrict__ WQT,
                                             unsigned short* __restrict__ qkv,
                                             unsigned short* __restrict__ vT) {
  __shared__ unsigned short sA[128][40];
  __shared__ unsigned short sB[128][40];
  const int t = threadIdx.x;
  const int col0 = blockIdx.x * 128;
  const int row0 = blockIdx.y * 128;
  const int l = t & 63, w = t >> 6;
  const int wm = (w & 1) * 64, wn = (w >> 1) * 64;
  const int lm = l & 15, lq = l >> 4;
  const int srow = t >> 1, skc = (t & 1) * 16;
  f32x4 acc[4][4] = {};
  for (int k0 = 0; k0 < Dd; k0 += 32) {
    {  // A: x fp32 -> bf16
      const float* src = X + (size_t)(row0 + srow) * Dd + k0 + skc;
      unsigned short tmp[16];
#pragma unroll
      for (int c4 = 0; c4 < 4; c4++) {
        float4 f = *(const float4*)(src + c4 * 4);
        tmp[c4 * 4 + 0] = f2b(f.x);
        tmp[c4 * 4 + 1] = f2b(f.y);
        tmp[c4 * 4 + 2] = f2b(f.z);
        tmp[c4 * 4 + 3] = f2b(f.w);
      }
      *(uint4*)&sA[srow][skc] = *(uint4*)tmp;
      *(uint4*)&sA[srow][skc + 8] = *(uint4*)(tmp + 8);
    }
    {  // B: WQT[col][k] bf16
      const unsigned short* srcB = WQT + (size_t)(col0 + srow) * Dd + k0 + skc;
      *(uint4*)&sB[srow][skc] = *(const uint4*)srcB;
      *(uint4*)&sB[srow][skc + 8] = *(const uint4*)(srcB + 8);
    }
    __syncthreads();
    bf16x8 af[4], bfr[4];
#pragma unroll
    for (int i = 0; i < 4; i++) af[i] = *(const bf16x8*)&sA[wm + 16 * i + lm][lq * 8];
#pragma unroll
    for (int j = 0; j < 4; j++) bfr[j] = *(const bf16x8*)&sB[wn + 16 * j + lm][lq * 8];
#pragma unroll
    for (int i = 0; i < 4; i++)
#pragma unroll
      for (int j = 0; j < 4; j++) acc[i][j] = MFMA(af[i], bfr[j], acc[i][j]);
    __syncthreads();
  }
  const bool isv = (col0 >= 2 * INNER);
#pragma unroll
  for (int i = 0; i < 4; i++) {
    const int rbase = row0 + wm + 16 * i + lq * 4;
#pragma unroll
    for (int j = 0; j < 4; j++) {
      const int col = col0 + wn + 16 * j + lm;
#pragma unroll
      for (int r = 0; r < 4; r++) {
        unsigned short hv = f2b(acc[i][j][r]);
        const int row = rbase + r;
        if (!isv) {
          qkv[(size_t)row * QW + col] = hv;
        } else {
          const int b = row >> 10, mseq = row & 1023;
          const int gd = col - 2 * INNER;
          vT[(((size_t)(b * Hh + (gd >> 6))) * DH + (gd & 63)) * Nn + mseq] = hv;
        }
      }
    }
  }
}

// ---------------- k_vsum: vsum[b,g,d] = sum_m v (from vT) ------------------
__global__ __launch_bounds__(256) void k_vsum(const unsigned short* __restrict__ vT,
                                              float* __restrict__ vsum) {
  const int bg = blockIdx.x;
  const int d = threadIdx.x >> 2, qq = threadIdx.x & 3;
  __shared__ float red[64][4];
  const unsigned short* p = vT + ((size_t)bg * DH + d) * Nn + qq * 256;
  float s = 0.f;
  for (int m = 0; m < 256; m += 4) {
    uint2 rr = *(const uint2*)(p + m);
    s += b2f((unsigned short)(rr.x & 0xffff)) + b2f((unsigned short)(rr.x >> 16)) +
         b2f((unsigned short)(rr.y & 0xffff)) + b2f((unsigned short)(rr.y >> 16));
  }
  red[d][qq] = s;
  __syncthreads();
  if (threadIdx.x < 64)
    vsum[(size_t)bg * DH + threadIdx.x] =
        red[threadIdx.x][0] + red[threadIdx.x][1] + red[threadIdx.x][2] + red[threadIdx.x][3];
}

// ---------------- K2: fused rowsum + S + mix + stats + S@V (MFMA) ----------
// grid (8 b, 32 n-tiles); block 512 = 8 waves; wave w = head h = group g.
__global__ __launch_bounds__(512, 2) void k_attn(const unsigned short* __restrict__ qkv,
                                                 const unsigned short* __restrict__ vT,
                                                 const float* __restrict__ conv_w,
                                                 float* __restrict__ O1,
                                                 float* __restrict__ stats) {
  __shared__ unsigned short sQ[8][32][88];   // 45,056 B (A-layout, 2-way banks)
  __shared__ unsigned short sKV[22528];      // 45,056 B  K:[h][m][88] / VT:[g][d][40]
  __shared__ float sS[8][32][36];            // 36,864 B
  __shared__ unsigned short sU[8][32][40];   // 20,480 B (A-layout for S@V)
  __shared__ float sRinv[8][32];
  __shared__ float sRed[8][16];
  const int b = blockIdx.x;  // linear wg id = b + 8*ntile -> %8 == b (XCD pin)
  const int n0 = blockIdx.y * 32;
  const int t = threadIdx.x;
  const int w = t >> 6, l = t & 63;
  const int lm = l & 15, lq = l >> 4;
  float cw[64];
#pragma unroll
  for (int i = 0; i < 64; i++) cw[i] = conv_w[i];

  {  // stage Q (all heads)
    const int row = t >> 1, kc = (t & 1) * 32;
    const int h = row >> 5, n = row & 31;
    const unsigned short* src = qkv + (size_t)(b * Nn + n0 + n) * QW + h * DH + kc;
    uint4 v0 = *(const uint4*)src, v1 = *(const uint4*)(src + 8);
    uint4 v2 = *(const uint4*)(src + 16), v3 = *(const uint4*)(src + 24);
    *(uint4*)&sQ[h][n][kc] = v0;
    *(uint4*)&sQ[h][n][kc + 8] = v1;
    *(uint4*)&sQ[h][n][kc + 16] = v2;
    *(uint4*)&sQ[h][n][kc + 24] = v3;
  }
  __syncthreads();

  // ---- pass 0: softmax denominators ----
  float psum[2][4] = {};
  for (int m0 = 0; m0 < Nn; m0 += 32) {
    {  // stage K
      const int row = t >> 1, kc = (t & 1) * 32;
      const int h = row >> 5, m = row & 31;
      const unsigned short* src = qkv + (size_t)(b * Nn + m0 + m) * QW + INNER + h * DH + kc;
      unsigned short* dst = &sKV[(h * 32 + m) * 88 + kc];
      uint4 v0 = *(const uint4*)src, v1 = *(const uint4*)(src + 8);
      uint4 v2 = *(const uint4*)(src + 16), v3 = *(const uint4*)(src + 24);
      *(uint4*)dst = v0;
      *(uint4*)(dst + 8) = v1;
      *(uint4*)(dst + 16) = v2;
      *(uint4*)(dst + 24) = v3;
    }
    __syncthreads();
    f32x4 lac[2][2] = {};
#pragma unroll
    for (int ks = 0; ks < 2; ks++) {
      bf16x8 a0 = *(const bf16x8*)&sQ[w][lm][ks * 32 + lq * 8];
      bf16x8 a1 = *(const bf16x8*)&sQ[w][16 + lm][ks * 32 + lq * 8];
      bf16x8 b0 = *(const bf16x8*)&sKV[(w * 32 + lm) * 88 + ks * 32 + lq * 8];
      bf16x8 b1 = *(const bf16x8*)&sKV[(w * 32 + 16 + lm) * 88 + ks * 32 + lq * 8];
      lac[0][0] = MFMA(a0, b0, lac[0][0]);
      lac[0][1] = MFMA(a0, b1, lac[0][1]);
      lac[1][0] = MFMA(a1, b0, lac[1][0]);
      lac[1][1] = MFMA(a1, b1, lac[1][1]);
    }
    __syncthreads();
#pragma unroll
    for (int i = 0; i < 2; i++)
#pragma unroll
      for (int j = 0; j < 2; j++)
#pragma unroll
        for (int r = 0; r < 4; r++) psum[i][r] += __expf(lac[i][j][r] * SCALE);
  }
#pragma unroll
  for (int i = 0; i < 2; i++)
#pragma unroll
    for (int r = 0; r < 4; r++) {
      float s = psum[i][r];
      s += __shfl_xor(s, 1);
      s += __shfl_xor(s, 2);
      s += __shfl_xor(s, 4);
      s += __shfl_xor(s, 8);
      if (lm == 0) sRinv[w][16 * i + lq * 4 + r] = 1.0f / s;
    }
  __syncthreads();
  float rv[2][4];
#pragma unroll
  for (int i = 0; i < 2; i++)
#pragma unroll
    for (int r = 0; r < 4; r++) rv[i][r] = sRinv[w][16 * i + lq * 4 + r];

  // ---- pass 1: S, mix, stats, S@V ----
  f32x4 oacc[2][4] = {};
  float su[8] = {}, su2[8] = {};
  const int mxn = t >> 4;           // 0..31
  const int mxm = (t & 15) * 2;     // 0..30 even
  for (int m0 = 0; m0 < Nn; m0 += 32) {
    {  // stage K
      const int row = t >> 1, kc = (t & 1) * 32;
      const int h = row >> 5, m = row & 31;
      const unsigned short* src = qkv + (size_t)(b * Nn + m0 + m) * QW + INNER + h * DH + kc;
      unsigned short* dst = &sKV[(h * 32 + m) * 88 + kc];
      uint4 v0 = *(const uint4*)src, v1 = *(const uint4*)(src + 8);
      uint4 v2 = *(const uint4*)(src + 16), v3 = *(const uint4*)(src + 24);
      *(uint4*)dst = v0;
      *(uint4*)(dst + 8) = v1;
      *(uint4*)(dst + 16) = v2;
      *(uint4*)(dst + 24) = v3;
    }
    __syncthreads();
    f32x4 lac[2][2] = {};
#pragma unroll
    for (int ks = 0; ks < 2; ks++) {
      bf16x8 a0 = *(const bf16x8*)&sQ[w][lm][ks * 32 + lq * 8];
      bf16x8 a1 = *(const bf16x8*)&sQ[w][16 + lm][ks * 32 + lq * 8];
      bf16x8 b0 = *(const bf16x8*)&sKV[(w * 32 + lm) * 88 + ks * 32 + lq * 8];
      bf16x8 b1 = *(const bf16x8*)&sKV[(w * 32 + 16 + lm) * 88 + ks * 32 + lq * 8];
      lac[0][0] = MFMA(a0, b0, lac[0][0]);
      lac[0][1] = MFMA(a0, b1, lac[0][1]);
      lac[1][0] = MFMA(a1, b0, lac[1][0]);
      lac[1][1] = MFMA(a1, b1, lac[1][1]);
    }
#pragma unroll
    for (int i = 0; i < 2; i++)
#pragma unroll
      for (int j = 0; j < 2; j++)
#pragma unroll
        for (int r = 0; r < 4; r++)
          sS[w][16 * i + lq * 4 + r][16 * j + lm] = __expf(lac[i][j][r] * SCALE) * rv[i][r];
    __syncthreads();
    {  // stage VT (overwrites sKV): [g][d][m] pad 40
      const unsigned short* src = vT + ((size_t)(b * Hh + (t >> 6)) * DH + (t & 63)) * Nn + m0;
      unsigned short* dst = &sKV[((t >> 6) * 64 + (t & 63)) * 40];
      uint4 v0 = *(const uint4*)src, v1 = *(const uint4*)(src + 8);
      uint4 v2 = *(const uint4*)(src + 16), v3 = *(const uint4*)(src + 24);
      *(uint4*)dst = v0;
      *(uint4*)(dst + 8) = v1;
      *(uint4*)(dst + 16) = v2;
      *(uint4*)(dst + 24) = v3;
    }
    {  // conv mix (fp32) + stats + sU (bf16)
      float2 sv[8];
#pragma unroll
      for (int h = 0; h < 8; h++) sv[h] = *(const float2*)&sS[h][mxn][mxm];
#pragma unroll
      for (int g = 0; g < 8; g++) {
        float u0 = 0.f, u1 = 0.f;
#pragma unroll
        for (int h = 0; h < 8; h++) {
          u0 += cw[g * 8 + h] * sv[h].x;
          u1 += cw[g * 8 + h] * sv[h].y;
        }
        su[g] += u0 + u1;
        su2[g] += u0 * u0 + u1 * u1;
        unsigned pk = (unsigned)f2b(u0) | ((unsigned)f2b(u1) << 16);
        *(unsigned*)&sU[g][mxn][mxm] = pk;
      }
    }
    __syncthreads();
    {  // S@V: A = sU[w], B = sVT[w]
      bf16x8 ua0 = *(const bf16x8*)&sU[w][lm][lq * 8];
      bf16x8 ua1 = *(const bf16x8*)&sU[w][16 + lm][lq * 8];
#pragma unroll
      for (int j = 0; j < 4; j++) {
        bf16x8 vb = *(const bf16x8*)&sKV[(w * 64 + 16 * j + lm) * 40 + lq * 8];
        oacc[0][j] = MFMA(ua0, vb, oacc[0][j]);
        oacc[1][j] = MFMA(ua1, vb, oacc[1][j]);
      }
    }
    __syncthreads();
  }
  // write O1
#pragma unroll
  for (int i = 0; i < 2; i++) {
    const int n = n0 + 16 * i + lq * 4;
#pragma unroll
    for (int j = 0; j < 4; j++) {
      float* dst = O1 + (((size_t)(b * Hh + w)) * Nn + n) * DH + 16 * j + lm;
#pragma unroll
      for (int r = 0; r < 4; r++) dst[(size_t)r * DH] = oacc[i][j][r];
    }
  }
  // stats reduce
#pragma unroll
  for (int g = 0; g < 8; g++) {
    float a = su[g], q = su2[g];
    for (int off = 32; off; off >>= 1) {
      a += __shfl_down(a, off);
      q += __shfl_down(q, off);
    }
    if (l == 0) {
      sRed[w][g] = a;
      sRed[w][8 + g] = q;
    }
  }
  __syncthreads();
  if (t < 16) {
    float s = 0.f;
#pragma unroll
    for (int ww = 0; ww < 8; ww++) s += sRed[ww][t];
    atomicAdd(&stats[t], s);
  }
}

// ---------------- K3: alpha/const --------------------------------------
__global__ void k_alpha(const float* __restrict__ stats, const float* __restrict__ bn_gamma,
                        const float* __restrict__ bn_beta, float* __restrict__ ac) {
  const int g = threadIdx.x;
  if (g < 8) {
    const float cnt = (float)Bz * (float)Nn * (float)Nn;
    float Eu = stats[g] / cnt;
    float Eu2 = stats[8 + g] / cnt;
    float inv = rsqrtf(Eu2 - Eu * Eu + BN_EPS);
    float alpha = bn_gamma[g] * inv;
    ac[g] = alpha;
    ac[8 + g] = bn_beta[g] - Eu * alpha;
  }
}

// ---------------- K4: out = (alpha*O1 + c*vsum) @ w_out + b_out (MFMA) -----
__global__ __launch_bounds__(256) void k_out(const float* __restrict__ O1,
                                             const float* __restrict__ vsum,
                                             const float* __restrict__ ac,
                                             const unsigned short* __restrict__ WOT,
                                             const float* __restrict__ bout,
                                             float* __restrict__ out) {
  __shared__ unsigned short sA[128][40];
  __shared__ unsigned short sB[128][40];
  __shared__ float sAl[16];
  const int t = threadIdx.x;
  if (t < 16) sAl[t] = ac[t];
  const int col0 = blockIdx.x * 128, row0 = blockIdx.y * 128;
  const int l = t & 63, w = t >> 6;
  const int wm = (w & 1) * 64, wn = (w >> 1) * 64;
  const int lm = l & 15, lq = l >> 4;
  const int srow = t >> 1, skc = (t & 1) * 16;
  const int b = row0 >> 10;
  const int nn = (row0 + srow) & 1023;
  f32x4 acc[4][4] = {};
  __syncthreads();
  for (int k0 = 0; k0 < INNER; k0 += 32) {
    {  // A: affine(O1) -> bf16
      const int k = k0 + skc;
      const int g = k >> 6, dd = k & 63;
      const float al = sAl[g], cc = sAl[8 + g];
      const float* op = O1 + (((size_t)(b * Hh + g)) * Nn + nn) * DH + dd;
      const float* vp = vsum + ((size_t)(b * Hh + g)) * DH + dd;
      unsigned short tmp[16];
#pragma unroll
      for (int c4 = 0; c4 < 4; c4++) {
        float4 o4 = *(const float4*)(op + c4 * 4);
        float4 v4 = *(const float4*)(vp + c4 * 4);
        tmp[c4 * 4 + 0] = f2b(al * o4.x + cc * v4.x);
        tmp[c4 * 4 + 1] = f2b(al * o4.y + cc * v4.y);
        tmp[c4 * 4 + 2] = f2b(al * o4.z + cc * v4.z);
        tmp[c4 * 4 + 3] = f2b(al * o4.w + cc * v4.w);
      }
      *(uint4*)&sA[srow][skc] = *(uint4*)tmp;
      *(uint4*)&sA[srow][skc + 8] = *(uint4*)(tmp + 8);
    }
    {  // B: WOT[col][k]
      const unsigned short* srcB = WOT + (size_t)(col0 + srow) * INNER + k0 + skc;
      *(uint4*)&sB[srow][skc] = *(const uint4*)srcB;
      *(uint4*)&sB[srow][skc + 8] = *(const uint4*)(srcB + 8);
    }
    __syncthreads();
    bf16x8 af[4], bfr[4];
#pragma unroll
    for (int i = 0; i < 4; i++) af[i] = *(const bf16x8*)&sA[wm + 16 * i + lm][lq * 8];
#pragma unroll
    for (int j = 0; j < 4; j++) bfr[j] = *(const bf16x8*)&sB[wn + 16 * j + lm][lq * 8];
#pragma unroll
    for (int i = 0; i < 4; i++)
#pragma unroll
      for (int j = 0; j < 4; j++) acc[i][j] = MFMA(af[i], bfr[j], acc[i][j]);
    __syncthreads();
  }
#pragma unroll
  for (int j = 0; j < 4; j++) {
    const int col = col0 + wn + 16 * j + lm;
    const float bo = bout[col];
#pragma unroll
    for (int i = 0; i < 4; i++) {
      const int rbase = row0 + wm + 16 * i + lq * 4;
#pragma unroll
      for (int r = 0; r < 4; r++) out[(size_t)(rbase + r) * Dd + col] = acc[i][j][r] + bo;
    }
  }
}

extern "C" void kernel_launch(void* const* d_in, const int* in_sizes, int n_in,
                              void* d_out, int out_size, void* d_ws, size_t ws_size,
                              hipStream_t stream) {
  const float* x = (const float*)d_in[0];
  const float* w_qkv = (const float*)d_in[1];
  const float* conv_w = (const float*)d_in[2];
  // d_in[3] = conv_b : cancels in train-mode BN.
  const float* bn_gamma = (const float*)d_in[4];
  const float* bn_beta = (const float*)d_in[5];
  const float* w_out = (const float*)d_in[6];
  const float* b_out = (const float*)d_in[7];
  char* ws = (char*)d_ws;
  unsigned short* QKV = (unsigned short*)(ws + WB_QKV);
  unsigned short* VT = (unsigned short*)(ws + WB_VT);
  unsigned short* WQT = (unsigned short*)(ws + WB_WQT);
  unsigned short* WOT = (unsigned short*)(ws + WB_WOT);
  float* O1 = (float*)(ws + WB_O1);
  float* VSUM = (float*)(ws + WB_VSUM);
  float* STATS = (float*)(ws + WB_STATS);
  float* AC = (float*)(ws + WB_AC);

  hipMemsetAsync(STATS, 0, 64, stream);
  k_transpose<<<dim3(48, 16), 256, 0, stream>>>(w_qkv, WQT, 512, 1536);
  k_transpose<<<dim3(16, 16), 256, 0, stream>>>(w_out, WOT, 512, 512);
  k_qkv<<<dim3(12, 64), 256, 0, stream>>>(x, WQT, QKV, VT);
  k_vsum<<<64, 256, 0, stream>>>(VT, VSUM);
  k_attn<<<dim3(8, 32), 512, 0, stream>>>(QKV, VT, conv_w, O1, STATS);
  k_alpha<<<1, 64, 0, stream>>>(STATS, bn_gamma, bn_beta, AC);
  k_out<<<dim3(4, 64), 256, 0, stream>>>(O1, VSUM, AC, WOT, b_out, (float*)d_out);
}

// Round 3
// 277.339 us; speedup vs baseline: 3.3514x; 1.1452x over previous
//
#include <hip/hip_runtime.h>
#include <math.h>

// ReAttention round 3: split attention into S-generate (global bf16 S~) +
// mix/stats/S@V. B=8 N=1024 D=512 H=8 dh=64 inner=512.
//
//  - conv bias cancels in train-mode BN (shifts mean only).
//  - attn'' = alpha_g*u_g + c_g ; u_g = sum_h conv_w[g,h]*S_h
//  - out_inner = alpha_g*O1 + c_g*vsum ; O1 = u @ v  (alpha-independent)
//  - k_sgen writes UNNORMALIZED S~ = exp(logit/8) bf16 + rinv (fp32);
//    k_mixsv normalizes inside the conv mix (rinv folded per-row).

#define Bz 8
#define Nn 1024
#define Dd 512
#define Hh 8
#define DH 64
#define INNER 512
#define QW 1536
#define SCALE 0.125f
#define BN_EPS 1e-5f

typedef short bf16x8 __attribute__((ext_vector_type(8)));
typedef float f32x4 __attribute__((ext_vector_type(4)));

#define MFMA(a, b, c) __builtin_amdgcn_mfma_f32_16x16x32_bf16((a), (b), (c), 0, 0, 0)

__device__ __forceinline__ unsigned short f2b(float f) {
  union { float f; unsigned u; } v; v.f = f;
  unsigned r = v.u + 0x7fffu + ((v.u >> 16) & 1u);
  return (unsigned short)(r >> 16);
}
__device__ __forceinline__ float b2f(unsigned short s) {
  union { unsigned u; float f; } v; v.u = ((unsigned)s) << 16;
  return v.f;
}

// ws layout (bytes)
#define WB_QKV 0u                           // 8192*1536*2 = 25,165,824 (q,k)
#define WB_VT (WB_QKV + 25165824u)          // 8,388,608
#define WB_WQT (WB_VT + 8388608u)           // 1,572,864
#define WB_WOT (WB_WQT + 1572864u)          // 524,288
#define WB_O1 (WB_WOT + 524288u)            // 16,777,216
#define WB_SG (WB_O1 + 16777216u)           // 64*1M*2 = 134,217,728
#define WB_RINV (WB_SG + 134217728u)        // 64*1024*4 = 262,144
#define WB_VSUM (WB_RINV + 262144u)         // 16,384
#define WB_STATS (WB_VSUM + 16384u)         // 64
#define WB_AC (WB_STATS + 64u)              // 64

// ---------------- transpose fp32 -> bf16: dst[C][R] = src[R][C]^T ----------
__global__ __launch_bounds__(256) void k_transpose(const float* __restrict__ src,
                                                   unsigned short* __restrict__ dst,
                                                   int R, int C) {
  __shared__ float tile[32][33];
  const int tc = blockIdx.x * 32, tr = blockIdx.y * 32;
  const int lx = threadIdx.x & 31, ly = threadIdx.x >> 5;
#pragma unroll
  for (int i = 0; i < 32; i += 8)
    tile[ly + i][lx] = src[(size_t)(tr + ly + i) * C + tc + lx];
  __syncthreads();
#pragma unroll
  for (int i = 0; i < 32; i += 8)
    dst[(size_t)(tc + ly + i) * R + tr + lx] = f2b(tile[lx][ly + i]);
}

// ---------------- K0: qkv = x @ w_qkv (bf16 MFMA) --------------------------
// q,k -> qkv[row][col]; v -> vT[b][g][d][m]. LDS round-trip epilogue for
// fully-coalesced 128B stores. q/k blocks accumulate transposed (cols in
// regs); v blocks accumulate normal (m rows in regs).
__global__ __launch_bounds__(256) void k_qkv(const float* __restrict__ X,
                                             const unsigned short* __restrict__ WQT,
                                             unsigned short* __restrict__ qkv,
                                             unsigned short* __restrict__ vT) {
  extern __shared__ char smem[];
  unsigned short(*sA)[40] = (unsigned short(*)[40])smem;
  unsigned short(*sB)[40] = (unsigned short(*)[40])(smem + 128 * 40 * 2);
  unsigned short* sEp = (unsigned short*)smem;  // 128*136 after loop
  const int t = threadIdx.x;
  const int col0 = blockIdx.x * 128;
  const int row0 = blockIdx.y * 128;
  const bool isqk = (col0 < 2 * INNER);
  const int l = t & 63, w = t >> 6;
  const int wm = (w & 1) * 64, wn = (w >> 1) * 64;
  const int lm = l & 15, lq = l >> 4;
  const int srow = t >> 1, skc = (t & 1) * 16;
  f32x4 acc[4][4] = {};
  for (int k0 = 0; k0 < Dd; k0 += 32) {
    {  // A: x fp32 -> bf16
      const float* src = X + (size_t)(row0 + srow) * Dd + k0 + skc;
      unsigned short tmp[16];
#pragma unroll
      for (int c4 = 0; c4 < 4; c4++) {
        float4 f = *(const float4*)(src + c4 * 4);
        tmp[c4 * 4 + 0] = f2b(f.x);
        tmp[c4 * 4 + 1] = f2b(f.y);
        tmp[c4 * 4 + 2] = f2b(f.z);
        tmp[c4 * 4 + 3] = f2b(f.w);
      }
      *(uint4*)&sA[srow][skc] = *(uint4*)tmp;
      *(uint4*)&sA[srow][skc + 8] = *(uint4*)(tmp + 8);
    }
    {  // B: WQT[col][k] bf16
      const unsigned short* srcB = WQT + (size_t)(col0 + srow) * Dd + k0 + skc;
      *(uint4*)&sB[srow][skc] = *(const uint4*)srcB;
      *(uint4*)&sB[srow][skc + 8] = *(const uint4*)(srcB + 8);
    }
    __syncthreads();
    bf16x8 af[4], bfr[4];
#pragma unroll
    for (int i = 0; i < 4; i++) af[i] = *(const bf16x8*)&sA[wm + 16 * i + lm][lq * 8];
#pragma unroll
    for (int j = 0; j < 4; j++) bfr[j] = *(const bf16x8*)&sB[wn + 16 * j + lm][lq * 8];
    if (isqk) {  // acc[i=col-tile][j=row-tile] = D[qkv-col][x-row]
#pragma unroll
      for (int i = 0; i < 4; i++)
#pragma unroll
        for (int j = 0; j < 4; j++) acc[i][j] = MFMA(bfr[i], af[j], acc[i][j]);
    } else {  // acc[i=row-tile][j=col-tile] = D[x-row][qkv-col]
#pragma unroll
      for (int i = 0; i < 4; i++)
#pragma unroll
        for (int j = 0; j < 4; j++) acc[i][j] = MFMA(af[i], bfr[j], acc[i][j]);
    }
    __syncthreads();
  }
  if (isqk) {
    // sEp[x-row][136] <- packed 4 consecutive cols per b64 write
#pragma unroll
    for (int jc = 0; jc < 4; jc++)
#pragma unroll
      for (int ir = 0; ir < 4; ir++) {
        unsigned short us[4];
#pragma unroll
        for (int r = 0; r < 4; r++) us[r] = f2b(acc[jc][ir][r]);
        *(uint2*)&sEp[(wm + 16 * ir + lm) * 136 + wn + 16 * jc + 4 * lq] = *(uint2*)us;
      }
    __syncthreads();
    const int row = t >> 1, half = t & 1;
    const unsigned short* src = &sEp[row * 136 + half * 64];
    unsigned short* dst = qkv + (size_t)(row0 + row) * QW + col0 + half * 64;
#pragma unroll
    for (int c = 0; c < 8; c++) *(uint4*)(dst + c * 8) = *(const uint4*)(src + c * 8);
  } else {
    // sEp[col(gd)][136] <- packed 4 consecutive m per b64 write
#pragma unroll
    for (int ir = 0; ir < 4; ir++)
#pragma unroll
      for (int jc = 0; jc < 4; jc++) {
        unsigned short us[4];
#pragma unroll
        for (int r = 0; r < 4; r++) us[r] = f2b(acc[ir][jc][r]);
        *(uint2*)&sEp[(wn + 16 * jc + lm) * 136 + wm + 16 * ir + 4 * lq] = *(uint2*)us;
      }
    __syncthreads();
    const int row = t >> 1, half = t & 1;  // row = local col index
    const int gd = col0 - 2 * INNER + row;
    const int bq = row0 >> 10, mseq0 = row0 & 1023;
    const unsigned short* src = &sEp[row * 136 + half * 64];
    unsigned short* dst =
        vT + (((size_t)(bq * Hh + (gd >> 6)) * DH + (gd & 63)) << 10) + mseq0 + half * 64;
#pragma unroll
    for (int c = 0; c < 8; c++) *(uint4*)(dst + c * 8) = *(const uint4*)(src + c * 8);
  }
}

// ---------------- k_vsum: vsum[b,g,d] = sum_m v (from vT) ------------------
__global__ __launch_bounds__(256) void k_vsum(const unsigned short* __restrict__ vT,
                                              float* __restrict__ vsum) {
  const int bg = blockIdx.x;
  const int d = threadIdx.x >> 2, qq = threadIdx.x & 3;
  __shared__ float red[64][4];
  const unsigned short* p = vT + ((size_t)bg * DH + d) * Nn + qq * 256;
  float s = 0.f;
  for (int m = 0; m < 256; m += 4) {
    uint2 rr = *(const uint2*)(p + m);
    s += b2f((unsigned short)(rr.x & 0xffff)) + b2f((unsigned short)(rr.x >> 16)) +
         b2f((unsigned short)(rr.y & 0xffff)) + b2f((unsigned short)(rr.y >> 16));
  }
  red[d][qq] = s;
  __syncthreads();
  if (threadIdx.x < 64)
    vsum[(size_t)bg * DH + threadIdx.x] =
        red[threadIdx.x][0] + red[threadIdx.x][1] + red[threadIdx.x][2] + red[threadIdx.x][3];
}

// ---------------- kA: S~ = exp(QK^T/8) bf16 -> global, rinv ---------------
// grid (b=8, ntile=8, h=8); 512 thr = 8 waves, wave w: n rows w*16..w*16+15.
__global__ __launch_bounds__(512, 4) void k_sgen(const unsigned short* __restrict__ qkv,
                                                 unsigned short* __restrict__ Sg,
                                                 float* __restrict__ rinvG) {
  __shared__ unsigned short sK[64 * 80];      // 10,240 B
  __shared__ unsigned short sSout[128 * 72];  // 18,432 B
  const int b = blockIdx.x, ntile = blockIdx.y, h = blockIdx.z;
  const int n0 = ntile * 128;
  const int t = threadIdx.x;
  const int w = t >> 6, l = t & 63;
  const int lm = l & 15, lq = l >> 4;
  // Q frags (held in regs across the m loop): lane lm -> n = n0+w*16+lm
  bf16x8 qf[2];
  {
    const unsigned short* qp =
        qkv + (size_t)(b * Nn + n0 + w * 16 + lm) * QW + h * DH + lq * 8;
    qf[0] = *(const bf16x8*)(qp);
    qf[1] = *(const bf16x8*)(qp + 32);
  }
  float psum = 0.f;
  for (int m0 = 0; m0 < Nn; m0 += 64) {
    {  // stage K chunk 64m x 64k (coalesced 128B rows)
      const int row = t >> 3, c = (t & 7) * 8;
      *(uint4*)&sK[row * 80 + c] =
          *(const uint4*)(qkv + (size_t)(b * Nn + m0 + row) * QW + INNER + h * DH + c);
    }
    __syncthreads();
    f32x4 lac[4] = {};
#pragma unroll
    for (int j = 0; j < 4; j++) {  // D[m=16j+4lq+r][n=n0+w*16+lm]
      bf16x8 a0 = *(const bf16x8*)&sK[(16 * j + lm) * 80 + lq * 8];
      bf16x8 a1 = *(const bf16x8*)&sK[(16 * j + lm) * 80 + 32 + lq * 8];
      lac[j] = MFMA(a0, qf[0], lac[j]);
      lac[j] = MFMA(a1, qf[1], lac[j]);
    }
#pragma unroll
    for (int j = 0; j < 4; j++) {
      unsigned short us[4];
#pragma unroll
      for (int r = 0; r < 4; r++) {
        float e = __expf(lac[j][r] * SCALE);
        psum += e;
        us[r] = f2b(e);
      }
      *(uint2*)&sSout[(w * 16 + lm) * 72 + 16 * j + 4 * lq] = *(uint2*)us;
    }
    __syncthreads();
    {  // coop store S~ tile (128 rows x 64 m), 32B/thread, 128B runs
      const int row = t >> 2, c = (t & 3) * 16;
      const unsigned short* src = &sSout[row * 72 + c];
      unsigned short* dst =
          Sg + ((size_t)(b * Hh + h) << 20) + (size_t)(n0 + row) * Nn + m0 + c;
      *(uint4*)dst = *(const uint4*)src;
      *(uint4*)(dst + 8) = *(const uint4*)(src + 8);
    }
  }
  psum += __shfl_xor(psum, 16);
  psum += __shfl_xor(psum, 32);
  if (lq == 0) rinvG[(size_t)(b * Hh + h) * Nn + n0 + w * 16 + lm] = 1.0f / psum;
}

// ---------------- kB: mix (normalize+conv+stats) + S@V -> O1 --------------
// grid (b=8, ntile=64); 512 thr = 8 waves; wave w = group g.
__global__ __launch_bounds__(512, 4) void k_mixsv(const unsigned short* __restrict__ Sg,
                                                  const unsigned short* __restrict__ vT,
                                                  const float* __restrict__ rinvG,
                                                  const float* __restrict__ conv_w,
                                                  float* __restrict__ O1,
                                                  float* __restrict__ stats) {
  __shared__ unsigned short sU[8 * 16 * 72];  // 18,432 B
  __shared__ float sRed[8][16];
  const int b = blockIdx.x;
  const int n0 = blockIdx.y * 16;
  const int t = threadIdx.x;
  const int w = t >> 6, l = t & 63;
  const int lm = l & 15, lq = l >> 4;
  const int mxn = t >> 5, mxm = (t & 31) * 2;
  float cw[64];
#pragma unroll
  for (int i = 0; i < 64; i++) cw[i] = conv_w[i];  // uniform -> SGPRs
  float rv[8];
#pragma unroll
  for (int h = 0; h < 8; h++) rv[h] = rinvG[(size_t)(b * Hh + h) * Nn + n0 + mxn];
  f32x4 oacc[4] = {};
  float su[8] = {}, su2[8] = {};
  for (int m0 = 0; m0 < Nn; m0 += 64) {
    {  // mix: normalize + conv + stats -> sU (bf16)
      float sx[8], sy[8];
#pragma unroll
      for (int h = 0; h < 8; h++) {
        unsigned pk = *(const unsigned*)(Sg + ((size_t)(b * Hh + h) << 20) +
                                         (size_t)(n0 + mxn) * Nn + m0 + mxm);
        sx[h] = b2f((unsigned short)(pk & 0xffff)) * rv[h];
        sy[h] = b2f((unsigned short)(pk >> 16)) * rv[h];
      }
#pragma unroll
      for (int g = 0; g < 8; g++) {
        float u0 = 0.f, u1 = 0.f;
#pragma unroll
        for (int h = 0; h < 8; h++) {
          u0 += cw[g * 8 + h] * sx[h];
          u1 += cw[g * 8 + h] * sy[h];
        }
        su[g] += u0 + u1;
        su2[g] += u0 * u0 + u1 * u1;
        *(unsigned*)&sU[(g * 16 + mxn) * 72 + mxm] =
            (unsigned)f2b(u0) | ((unsigned)f2b(u1) << 16);
      }
    }
    __syncthreads();
    {  // S@V: A = sU[g=w], B = vT frags direct from global (L2-hot)
      bf16x8 uf0 = *(const bf16x8*)&sU[(w * 16 + lm) * 72 + lq * 8];
      bf16x8 uf1 = *(const bf16x8*)&sU[(w * 16 + lm) * 72 + 32 + lq * 8];
#pragma unroll
      for (int j = 0; j < 4; j++) {
        const unsigned short* vp =
            vT + (((size_t)(b * Hh + w) * DH + 16 * j + lm) << 10) + m0 + lq * 8;
        bf16x8 v0 = *(const bf16x8*)vp;
        bf16x8 v1 = *(const bf16x8*)(vp + 32);
        oacc[j] = MFMA(uf0, v0, oacc[j]);
        oacc[j] = MFMA(uf1, v1, oacc[j]);
      }
    }
    __syncthreads();
  }
  // O1 write: rows n = n0+4lq+r, cols d = 16j+lm
#pragma unroll
  for (int j = 0; j < 4; j++)
#pragma unroll
    for (int r = 0; r < 4; r++)
      O1[((size_t)(b * Hh + w) * Nn + n0 + lq * 4 + r) * DH + 16 * j + lm] = oacc[j][r];
  // stats reduce
#pragma unroll
  for (int g = 0; g < 8; g++) {
    float a = su[g], q = su2[g];
    for (int off = 32; off; off >>= 1) {
      a += __shfl_down(a, off);
      q += __shfl_down(q, off);
    }
    if (l == 0) {
      sRed[w][g] = a;
      sRed[w][8 + g] = q;
    }
  }
  __syncthreads();
  if (t < 16) {
    float s = 0.f;
#pragma unroll
    for (int ww = 0; ww < 8; ww++) s += sRed[ww][t];
    atomicAdd(&stats[t], s);
  }
}

// ---------------- K3: alpha/const --------------------------------------
__global__ void k_alpha(const float* __restrict__ stats, const float* __restrict__ bn_gamma,
                        const float* __restrict__ bn_beta, float* __restrict__ ac) {
  const int g = threadIdx.x;
  if (g < 8) {
    const float cnt = (float)Bz * (float)Nn * (float)Nn;
    float Eu = stats[g] / cnt;
    float Eu2 = stats[8 + g] / cnt;
    float inv = rsqrtf(Eu2 - Eu * Eu + BN_EPS);
    float alpha = bn_gamma[g] * inv;
    ac[g] = alpha;
    ac[8 + g] = bn_beta[g] - Eu * alpha;
  }
}

// ---------------- K4: out = (alpha*O1 + c*vsum) @ w_out + b_out (MFMA) -----
__global__ __launch_bounds__(256) void k_out(const float* __restrict__ O1,
                                             const float* __restrict__ vsum,
                                             const float* __restrict__ ac,
                                             const unsigned short* __restrict__ WOT,
                                             const float* __restrict__ bout,
                                             float* __restrict__ out) {
  __shared__ unsigned short sA[128][40];
  __shared__ unsigned short sB[128][40];
  __shared__ float sAl[16];
  const int t = threadIdx.x;
  if (t < 16) sAl[t] = ac[t];
  const int col0 = blockIdx.x * 128, row0 = blockIdx.y * 128;
  const int l = t & 63, w = t >> 6;
  const int wm = (w & 1) * 64, wn = (w >> 1) * 64;
  const int lm = l & 15, lq = l >> 4;
  const int srow = t >> 1, skc = (t & 1) * 16;
  const int b = row0 >> 10;
  const int nn = (row0 + srow) & 1023;
  f32x4 acc[4][4] = {};
  __syncthreads();
  for (int k0 = 0; k0 < INNER; k0 += 32) {
    {  // A: affine(O1) -> bf16
      const int k = k0 + skc;
      const int g = k >> 6, dd = k & 63;
      const float al = sAl[g], cc = sAl[8 + g];
      const float* op = O1 + ((size_t)(b * Hh + g) * Nn + nn) * DH + dd;
      const float* vp = vsum + (size_t)(b * Hh + g) * DH + dd;
      unsigned short tmp[16];
#pragma unroll
      for (int c4 = 0; c4 < 4; c4++) {
        float4 o4 = *(const float4*)(op + c4 * 4);
        float4 v4 = *(const float4*)(vp + c4 * 4);
        tmp[c4 * 4 + 0] = f2b(al * o4.x + cc * v4.x);
        tmp[c4 * 4 + 1] = f2b(al * o4.y + cc * v4.y);
        tmp[c4 * 4 + 2] = f2b(al * o4.z + cc * v4.z);
        tmp[c4 * 4 + 3] = f2b(al * o4.w + cc * v4.w);
      }
      *(uint4*)&sA[srow][skc] = *(uint4*)tmp;
      *(uint4*)&sA[srow][skc + 8] = *(uint4*)(tmp + 8);
    }
    {
      const unsigned short* srcB = WOT + (size_t)(col0 + srow) * INNER + k0 + skc;
      *(uint4*)&sB[srow][skc] = *(const uint4*)srcB;
      *(uint4*)&sB[srow][skc + 8] = *(const uint4*)(srcB + 8);
    }
    __syncthreads();
    bf16x8 af[4], bfr[4];
#pragma unroll
    for (int i = 0; i < 4; i++) af[i] = *(const bf16x8*)&sA[wm + 16 * i + lm][lq * 8];
#pragma unroll
    for (int j = 0; j < 4; j++) bfr[j] = *(const bf16x8*)&sB[wn + 16 * j + lm][lq * 8];
#pragma unroll
    for (int i = 0; i < 4; i++)
#pragma unroll
      for (int j = 0; j < 4; j++) acc[i][j] = MFMA(af[i], bfr[j], acc[i][j]);
    __syncthreads();
  }
#pragma unroll
  for (int j = 0; j < 4; j++) {
    const int col = col0 + wn + 16 * j + lm;
    const float bo = bout[col];
#pragma unroll
    for (int i = 0; i < 4; i++) {
      const int rbase = row0 + wm + 16 * i + lq * 4;
#pragma unroll
      for (int r = 0; r < 4; r++) out[(size_t)(rbase + r) * Dd + col] = acc[i][j][r] + bo;
    }
  }
}

extern "C" void kernel_launch(void* const* d_in, const int* in_sizes, int n_in,
                              void* d_out, int out_size, void* d_ws, size_t ws_size,
                              hipStream_t stream) {
  const float* x = (const float*)d_in[0];
  const float* w_qkv = (const float*)d_in[1];
  const float* conv_w = (const float*)d_in[2];
  // d_in[3] = conv_b : cancels in train-mode BN.
  const float* bn_gamma = (const float*)d_in[4];
  const float* bn_beta = (const float*)d_in[5];
  const float* w_out = (const float*)d_in[6];
  const float* b_out = (const float*)d_in[7];
  char* ws = (char*)d_ws;
  unsigned short* QKV = (unsigned short*)(ws + WB_QKV);
  unsigned short* VT = (unsigned short*)(ws + WB_VT);
  unsigned short* WQT = (unsigned short*)(ws + WB_WQT);
  unsigned short* WOT = (unsigned short*)(ws + WB_WOT);
  float* O1 = (float*)(ws + WB_O1);
  unsigned short* SG = (unsigned short*)(ws + WB_SG);
  float* RINV = (float*)(ws + WB_RINV);
  float* VSUM = (float*)(ws + WB_VSUM);
  float* STATS = (float*)(ws + WB_STATS);
  float* AC = (float*)(ws + WB_AC);

  hipMemsetAsync(STATS, 0, 64, stream);
  k_transpose<<<dim3(48, 16), 256, 0, stream>>>(w_qkv, WQT, 512, 1536);
  k_transpose<<<dim3(16, 16), 256, 0, stream>>>(w_out, WOT, 512, 512);
  k_qkv<<<dim3(12, 64), 256, 34816, stream>>>(x, WQT, QKV, VT);
  k_vsum<<<64, 256, 0, stream>>>(VT, VSUM);
  k_sgen<<<dim3(8, 8, 8), 512, 0, stream>>>(QKV, SG, RINV);
  k_mixsv<<<dim3(8, 64), 512, 0, stream>>>(SG, VT, RINV, conv_w, O1, STATS);
  k_alpha<<<1, 64, 0, stream>>>(STATS, bn_gamma, bn_beta, AC);
  k_out<<<dim3(4, 64), 256, 0, stream>>>(O1, VSUM, AC, WOT, b_out, (float*)d_out);
}